// Round 1
// 1268.569 us; speedup vs baseline: 1.1462x; 1.1462x over previous
//
#include <hip/hip_runtime.h>
#include <stdint.h>

typedef _Float16 half_t;
typedef _Float16 half8 __attribute__((ext_vector_type(8)));
typedef _Float16 half4v __attribute__((ext_vector_type(4)));
typedef float floatx4 __attribute__((ext_vector_type(4)));

#define M_TOT 8192
#define N_TOT 11008
#define K_TOT 4096

// ---------------- prolog 1: quantize activations fp32 -> f16 ----------------
// q = clamp(round(x / 0.02), -32768, 32767); |q| small, exact in f16.
__global__ __launch_bounds__(256) void quantize_kernel(
    const float* __restrict__ x, half_t* __restrict__ xq) {
  int i = blockIdx.x * blockDim.x + threadIdx.x;
  float4 v = ((const float4*)x)[i];
  float q0 = fminf(fmaxf(rintf(v.x / 0.02f), -32768.f), 32767.f);
  float q1 = fminf(fmaxf(rintf(v.y / 0.02f), -32768.f), 32767.f);
  float q2 = fminf(fmaxf(rintf(v.z / 0.02f), -32768.f), 32767.f);
  float q3 = fminf(fmaxf(rintf(v.w / 0.02f), -32768.f), 32767.f);
  half4v h;
  h.x = (half_t)q0; h.y = (half_t)q1; h.z = (half_t)q2; h.w = (half_t)q3;
  ((half4v*)xq)[i] = h;
}

// ---------------- prolog 2: weight int32 -> f16 ----------------
__global__ __launch_bounds__(256) void wconv_kernel(
    const int* __restrict__ w, half_t* __restrict__ wf) {
  int i = blockIdx.x * blockDim.x + threadIdx.x;
  int4 v = ((const int4*)w)[i];
  half4v h;
  h.x = (half_t)(float)v.x; h.y = (half_t)(float)v.y;
  h.z = (half_t)(float)v.z; h.w = (half_t)(float)v.w;
  ((half4v*)wf)[i] = h;
}

// ---------------- async 16B global->LDS ----------------
__device__ __forceinline__ void async16(const half_t* g, half_t* l) {
  __builtin_amdgcn_global_load_lds(
      (const __attribute__((address_space(1))) void*)g,
      (__attribute__((address_space(3))) void*)l, 16, 0, 0);
}

#define VMCNT(N) asm volatile("s_waitcnt vmcnt(" #N ")" ::: "memory")
#define BARX()                               \
  do {                                       \
    __builtin_amdgcn_s_barrier();            \
    __builtin_amdgcn_sched_barrier(0);       \
  } while (0)

// ---------------- main GEMM: 256x256 tile, 8-phase counted-vmcnt pipeline ----
// C[M,N] = A[M,K] * W[N,K]^T with fused dequant epilogue.
//
// 512 threads = 8 waves as 2(M) x 4(N); each wave owns a 128x64 output tile,
// acc[8][4] f32x4. K is processed in 64-wide K-tiles, each split into two
// 32-k halves. LDS = ring of 4 half-tile slots per operand:
//   slot(tile t, half h) = (2t+h) & 3 ; A slots 4x[256][32]f16, B same.
// Per 8-phase iteration (tiles t=2it, t+1):
//   ph g: (qm, computeSlot) = (g&1^1.., see table); 16 MFMA per phase.
//   compute slots: 0,0,1,1,2,2,3,3 ; stage slots: 3,3,0,0,1,1,2,2
//   stage stream stays 3 half-tiles (6 loads) ahead; vmcnt(6) before the
//   pre-MFMA barrier of every even phase establishes (with 2 barriers) the
//   cross-wave completion guarantee for the pair consumed 1-2 phases later.
//   WAR: a slot is staged exactly 1 phase after its last ds_read; the
//   end-of-phase barrier (all waves did lgkmcnt(0) pre-MFMA) makes it safe.
// LDS swizzle: 16B chunk kc of row r lives at slot kc ^ ((r ^ (r>>2)) & 3);
// staging keeps LDS dest LINEAR (global_load_lds constraint) and permutes the
// global source chunk instead. ds_read_b128: 16 lanes/kc-group hit 8 distinct
// bank-quads 2-way each -> conflict-free.
__global__ __launch_bounds__(512) void gemm_kernel(
    const half_t* __restrict__ A,    // [M, K] quantized activations (f16)
    const half_t* __restrict__ W,    // [N, K] weights (f16)
    const float* __restrict__ scale, // [N]
    const float* __restrict__ bias,  // [N]
    float* __restrict__ C) {         // [M, N]
  __shared__ __align__(16) half_t lds[65536];  // 128 KiB: A [0,32768) B rest

  const int tid = threadIdx.x;
  const int lane = tid & 63;
  const int wave = tid >> 6;
  const int wm = wave >> 2;  // 0..1
  const int wn = wave & 3;   // 0..3

  // XCD-chunked swizzle (1376 = 8*172 exact) + 4-bm grouping: each XCD gets
  // 4 consecutive bm panels x all 43 bn; 4 consecutive blocks share a W panel.
  int id = blockIdx.x;
  id = (id & 7) * 172 + (id >> 3);
  const int bm = ((id / 172) * 4 + ((id % 172) & 3)) * 256;
  const int bn = ((id % 172) >> 2) * 256;

  // ---- staging constants: thread owns linear chunks c0=tid, c1=tid+512 ----
  // chunk c -> row r=c>>2, phys slot pc=c&3, fetches global kc = pc ^ swz(r).
  const int c0 = tid, c1 = tid + 512;
  const int r0 = c0 >> 2, r1 = c1 >> 2;
  const int kc0 = (c0 & 3) ^ ((r0 ^ (r0 >> 2)) & 3);
  const int kc1 = (c1 & 3) ^ ((r1 ^ (r1 >> 2)) & 3);
  const half_t* agA0 = A + (size_t)(bm + r0) * K_TOT + kc0 * 8;
  const half_t* agA1 = A + (size_t)(bm + r1) * K_TOT + kc1 * 8;
  const half_t* agB0 = W + (size_t)(bn + r0) * K_TOT + kc0 * 8;
  const half_t* agB1 = W + (size_t)(bn + r1) * K_TOT + kc1 * 8;

#define STAGE_A(S, KOFF)                                  \
  do {                                                    \
    async16(agA0 + (KOFF), lds + (S)*8192 + c0 * 8);      \
    async16(agA1 + (KOFF), lds + (S)*8192 + c1 * 8);      \
  } while (0)
#define STAGE_B(S, KOFF)                                          \
  do {                                                            \
    async16(agB0 + (KOFF), lds + 32768 + (S)*8192 + c0 * 8);      \
    async16(agB1 + (KOFF), lds + 32768 + (S)*8192 + c1 * 8);      \
  } while (0)
#define NOSTAGE() (void)0
#define NOWAIT() (void)0

  // ---- fragment-read constants ----
  // lane reads rows (.. + i*16 + fr), logical chunk kq=lane>>4; the swizzle
  // term reduces to fr bits only ((r&3)=fr&3, ((r>>2)&3)=(fr>>2)&3).
  const int fr = lane & 15;
  const int kcs = (lane >> 4) ^ ((fr ^ (fr >> 2)) & 3);
  const int aoff = (wm * 128 + fr) * 32 + kcs * 8;           // + qm*2048 + i*512
  const int boff = 32768 + (wn * 64 + fr) * 32 + kcs * 8;    // + j*512

  floatx4 acc[8][4] = {};

#define PHASE(QM, CS, STAGE_STMT, WAIT_STMT)                              \
  do {                                                                    \
    half8 af[4], wf[4];                                                   \
    const half_t* ap = lds + (CS)*8192 + aoff + (QM)*2048;                \
    const half_t* bp = lds + (CS)*8192 + boff;                            \
    _Pragma("unroll") for (int i = 0; i < 4; ++i)                         \
        af[i] = *(const half8*)(ap + i * 512);                            \
    _Pragma("unroll") for (int j = 0; j < 4; ++j)                         \
        wf[j] = *(const half8*)(bp + j * 512);                            \
    STAGE_STMT;                                                           \
    WAIT_STMT;                                                            \
    BARX();                                                               \
    __builtin_amdgcn_s_setprio(1);                                        \
    _Pragma("unroll") for (int i = 0; i < 4; ++i)                         \
        _Pragma("unroll") for (int j = 0; j < 4; ++j)                     \
            acc[(QM)*4 + i][j] = __builtin_amdgcn_mfma_f32_16x16x32_f16(  \
                af[i], wf[j], acc[(QM)*4 + i][j], 0, 0, 0);               \
    __builtin_amdgcn_s_setprio(0);                                        \
    BARX();                                                               \
  } while (0)

  // ---- prologue: tile0 (slots 0,1) + tile1 k0 (slot 2); 12 loads issued,
  // vmcnt(6) -> first 3 half-tiles (incl. pair(0,k0)) complete.
  STAGE_A(0, 0);  STAGE_B(0, 0);
  STAGE_A(1, 32); STAGE_B(1, 32);
  STAGE_A(2, 64); STAGE_B(2, 64);
  VMCNT(6);
  BARX();

  // ---- main loop: 31 full iterations (tiles 0..61 computed, stages 2..63) --
  for (int it = 0; it < 31; ++it) {
    const int kb = it * 128;
    PHASE(0, 0, STAGE_A(3, kb + 96),  NOWAIT());  // g1: stage A(t+1,k1)
    PHASE(1, 0, STAGE_B(3, kb + 96),  VMCNT(6));  // g2: stage B(t+1,k1)
    PHASE(0, 1, STAGE_A(0, kb + 128), NOWAIT());  // g3: stage A(t+2,k0)
    PHASE(1, 1, STAGE_B(0, kb + 128), VMCNT(6));  // g4
    PHASE(0, 2, STAGE_A(1, kb + 160), NOWAIT());  // g5: stage A(t+2,k1)
    PHASE(1, 2, STAGE_B(1, kb + 160), VMCNT(6));  // g6
    PHASE(0, 3, STAGE_A(2, kb + 192), NOWAIT());  // g7: stage A(t+3,k0)
    PHASE(1, 3, STAGE_B(2, kb + 192), VMCNT(6));  // g8
  }

  // ---- peeled last iteration (tiles 62,63): only tile63.k1 left to stage;
  // drain 6 -> 4 -> 0.
  PHASE(0, 0, STAGE_A(3, 4064), NOWAIT());
  PHASE(1, 0, STAGE_B(3, 4064), VMCNT(6));
  PHASE(0, 1, NOSTAGE(), NOWAIT());
  PHASE(1, 1, NOSTAGE(), VMCNT(4));
  PHASE(0, 2, NOSTAGE(), NOWAIT());
  PHASE(1, 2, NOSTAGE(), VMCNT(0));
  PHASE(0, 3, NOSTAGE(), NOWAIT());
  PHASE(1, 3, NOSTAGE(), NOWAIT());

  // ---- epilogue: D col = lane&15 (n), row = (lane>>4)*4 + reg (m) ----
  const int row0 = bm + wm * 128 + (lane >> 4) * 4;
  const int col0 = bn + wn * 64 + (lane & 15);
#pragma unroll
  for (int j = 0; j < 4; ++j) {
    const int col = col0 + j * 16;
    const float alpha = 0.02f * scale[col];
    const float beta = bias[col];
#pragma unroll
    for (int i8 = 0; i8 < 8; ++i8) {
      float* cp = C + (size_t)(row0 + i8 * 16) * N_TOT + col;
#pragma unroll
      for (int r = 0; r < 4; ++r)
        cp[(size_t)r * N_TOT] = acc[i8][j][r] * alpha + beta;
    }
  }
}

extern "C" void kernel_launch(void* const* d_in, const int* in_sizes, int n_in,
                              void* d_out, int out_size, void* d_ws,
                              size_t ws_size, hipStream_t stream) {
  const float* x = (const float*)d_in[0];     // [4,2048,4096] fp32
  const int* w = (const int*)d_in[1];         // [11008,4096] int32
  const float* scale = (const float*)d_in[2]; // [11008]
  const float* bias = (const float*)d_in[3];  // [1,11008]
  float* out = (float*)d_out;                 // [4,2048,11008] fp32

  half_t* xq = (half_t*)d_ws;                                    // 64 MB
  half_t* wq = (half_t*)((char*)d_ws + (size_t)M_TOT * K_TOT * sizeof(half_t));

  quantize_kernel<<<32768, 256, 0, stream>>>(x, xq);
  wconv_kernel<<<44032, 256, 0, stream>>>(w, wq);

  // 8192/256 = 32 ; 11008/256 = 43 ; 32*43 = 1376 blocks (8*172, XCD-exact)
  gemm_kernel<<<1376, 512, 0, stream>>>(xq, wq, scale, bias, out);
}

// Round 2
// 1197.661 us; speedup vs baseline: 1.2141x; 1.0592x over previous
//
#include <hip/hip_runtime.h>
#include <stdint.h>

typedef _Float16 half_t;
typedef _Float16 half8 __attribute__((ext_vector_type(8)));
typedef _Float16 half4v __attribute__((ext_vector_type(4)));
typedef float floatx4 __attribute__((ext_vector_type(4)));

#define M_TOT 8192
#define N_TOT 11008
#define K_TOT 4096

// ---------------- prolog 1: quantize activations fp32 -> f16 ----------------
// q = clamp(round(x / 0.02), -32768, 32767); |q| small, exact in f16.
__global__ __launch_bounds__(256) void quantize_kernel(
    const float* __restrict__ x, half_t* __restrict__ xq) {
  int i = blockIdx.x * blockDim.x + threadIdx.x;
  float4 v = ((const float4*)x)[i];
  float q0 = fminf(fmaxf(rintf(v.x / 0.02f), -32768.f), 32767.f);
  float q1 = fminf(fmaxf(rintf(v.y / 0.02f), -32768.f), 32767.f);
  float q2 = fminf(fmaxf(rintf(v.z / 0.02f), -32768.f), 32767.f);
  float q3 = fminf(fmaxf(rintf(v.w / 0.02f), -32768.f), 32767.f);
  half4v h;
  h.x = (half_t)q0; h.y = (half_t)q1; h.z = (half_t)q2; h.w = (half_t)q3;
  ((half4v*)xq)[i] = h;
}

// ---------------- prolog 2: weight int32 -> f16 ----------------
__global__ __launch_bounds__(256) void wconv_kernel(
    const int* __restrict__ w, half_t* __restrict__ wf) {
  int i = blockIdx.x * blockDim.x + threadIdx.x;
  int4 v = ((const int4*)w)[i];
  half4v h;
  h.x = (half_t)(float)v.x; h.y = (half_t)(float)v.y;
  h.z = (half_t)(float)v.z; h.w = (half_t)(float)v.w;
  ((half4v*)wf)[i] = h;
}

// ---------------- async 16B global->LDS ----------------
__device__ __forceinline__ void async16(const half_t* g, half_t* l) {
  __builtin_amdgcn_global_load_lds(
      (const __attribute__((address_space(1))) void*)g,
      (__attribute__((address_space(3))) void*)l, 16, 0, 0);
}

#define VMCNT(N) asm volatile("s_waitcnt vmcnt(" #N ")" ::: "memory")
#define BARX()                               \
  do {                                       \
    __builtin_amdgcn_s_barrier();            \
    __builtin_amdgcn_sched_barrier(0);       \
  } while (0)

// ---------------- main GEMM: 256x256 tile, 8-phase counted-vmcnt pipeline ----
// C[M,N] = A[M,K] * W[N,K]^T with fused dequant epilogue.
//
// 512 threads = 8 waves as 2(M) x 4(N); each wave owns a 128x64 output tile,
// acc[8][4] f32x4. K is processed in 64-wide K-tiles, each split into two
// 32-k halves. LDS = ring of 4 half-tile slots per operand:
//   slot(tile t, half h) = (2t+h) & 3 ; A slots 4x[256][32]f16, B same.
// Per 8-phase iteration (tiles t=2it, t+1):
//   compute slots: 0,0,1,1,2,2,3,3 ; stage slots: 3,3,0,0,1,1,2,2
//   stage stream stays 3 half-tiles (6 loads) ahead; vmcnt(6) before the
//   pre-MFMA barrier of every even phase establishes (with the barrier)
//   cross-wave completion for the pair consumed 1-2 phases later.
//   WAR: a slot is staged exactly 1 phase after its last ds_read; the
//   end-of-phase barrier (all waves did lgkmcnt(0) pre-MFMA) makes it safe.
// LDS swizzle [round-0 HW-verified conflict-free pattern, 0 SQ_LDS_BANK_CONFLICT]:
//   16B chunk kc of row r lives at phys slot kc ^ ((r>>1)&3).
//   (The (r^(r>>2))&3 variant measured 9.0e7 conflicts on the identical read
//   geometry -- period-8 repeating quad pattern is what the coalescer wants.)
// Staging keeps the LDS dest LINEAR (global_load_lds constraint) and permutes
// the global source chunk instead.
__global__ __launch_bounds__(512) void gemm_kernel(
    const half_t* __restrict__ A,    // [M, K] quantized activations (f16)
    const half_t* __restrict__ W,    // [N, K] weights (f16)
    const float* __restrict__ scale, // [N]
    const float* __restrict__ bias,  // [N]
    float* __restrict__ C) {         // [M, N]
  __shared__ __align__(16) half_t lds[65536];  // 128 KiB: A [0,32768) B rest

  const int tid = threadIdx.x;
  const int lane = tid & 63;
  const int wave = tid >> 6;
  const int wm = wave >> 2;  // 0..1
  const int wn = wave & 3;   // 0..3

  // XCD-chunked swizzle (1376 = 8*172 exact) + 4-bm grouping: each XCD gets
  // 4 consecutive bm panels x all 43 bn; 4 consecutive blocks share a W panel.
  int id = blockIdx.x;
  id = (id & 7) * 172 + (id >> 3);
  const int bm = ((id / 172) * 4 + ((id % 172) & 3)) * 256;
  const int bn = ((id % 172) >> 2) * 256;

  // ---- staging constants: thread owns linear chunks c0=tid, c1=tid+512 ----
  // chunk c -> row r=c>>2, phys slot pc=c&3, fetches global kc = pc ^ swz(r).
  const int c0 = tid, c1 = tid + 512;
  const int r0 = c0 >> 2, r1 = c1 >> 2;
  const int kc0 = (c0 & 3) ^ ((r0 >> 1) & 3);
  const int kc1 = (c1 & 3) ^ ((r1 >> 1) & 3);
  const half_t* agA0 = A + (size_t)(bm + r0) * K_TOT + kc0 * 8;
  const half_t* agA1 = A + (size_t)(bm + r1) * K_TOT + kc1 * 8;
  const half_t* agB0 = W + (size_t)(bn + r0) * K_TOT + kc0 * 8;
  const half_t* agB1 = W + (size_t)(bn + r1) * K_TOT + kc1 * 8;

#define STAGE_A(S, KOFF)                                  \
  do {                                                    \
    async16(agA0 + (KOFF), lds + (S)*8192 + c0 * 8);      \
    async16(agA1 + (KOFF), lds + (S)*8192 + c1 * 8);      \
  } while (0)
#define STAGE_B(S, KOFF)                                          \
  do {                                                            \
    async16(agB0 + (KOFF), lds + 32768 + (S)*8192 + c0 * 8);      \
    async16(agB1 + (KOFF), lds + 32768 + (S)*8192 + c1 * 8);      \
  } while (0)
#define NOSTAGE() (void)0
#define NOWAIT() (void)0

  // ---- fragment-read constants ----
  // lane reads rows (.. + i*16 + fr), logical chunk kq=lane>>4; the swizzle
  // term (row>>1)&3 reduces to (fr>>1)&3 (wm*64, qm*32, i*8 vanish mod 4).
  const int fr = lane & 15;
  const int kcs = (lane >> 4) ^ ((fr >> 1) & 3);
  const int aoff = (wm * 128 + fr) * 32 + kcs * 8;           // + qm*2048 + i*512
  const int boff = 32768 + (wn * 64 + fr) * 32 + kcs * 8;    // + j*512

  floatx4 acc[8][4] = {};

#define PHASE(QM, CS, STAGE_STMT, WAIT_STMT)                              \
  do {                                                                    \
    half8 af[4], wf[4];                                                   \
    const half_t* ap = lds + (CS)*8192 + aoff + (QM)*2048;                \
    const half_t* bp = lds + (CS)*8192 + boff;                            \
    _Pragma("unroll") for (int i = 0; i < 4; ++i)                         \
        af[i] = *(const half8*)(ap + i * 512);                            \
    _Pragma("unroll") for (int j = 0; j < 4; ++j)                         \
        wf[j] = *(const half8*)(bp + j * 512);                            \
    STAGE_STMT;                                                           \
    WAIT_STMT;                                                            \
    BARX();                                                               \
    __builtin_amdgcn_s_setprio(1);                                        \
    _Pragma("unroll") for (int i = 0; i < 4; ++i)                         \
        _Pragma("unroll") for (int j = 0; j < 4; ++j)                     \
            acc[(QM)*4 + i][j] = __builtin_amdgcn_mfma_f32_16x16x32_f16(  \
                af[i], wf[j], acc[(QM)*4 + i][j], 0, 0, 0);               \
    __builtin_amdgcn_s_setprio(0);                                        \
    BARX();                                                               \
  } while (0)

  // ---- prologue: tile0 (slots 0,1) + tile1 k0 (slot 2); 12 loads issued,
  // vmcnt(6) -> each wave's first 3 half-tiles (incl. pair(0,k0)) complete.
  STAGE_A(0, 0);  STAGE_B(0, 0);
  STAGE_A(1, 32); STAGE_B(1, 32);
  STAGE_A(2, 64); STAGE_B(2, 64);
  VMCNT(6);
  BARX();

  // ---- main loop: 31 full iterations (tiles 0..61 computed, stages 2..63) --
  for (int it = 0; it < 31; ++it) {
    const int kb = it * 128;
    PHASE(0, 0, STAGE_A(3, kb + 96),  NOWAIT());  // g1: stage A(t+1,k1)
    PHASE(1, 0, STAGE_B(3, kb + 96),  VMCNT(6));  // g2: stage B(t+1,k1)
    PHASE(0, 1, STAGE_A(0, kb + 128), NOWAIT());  // g3: stage A(t+2,k0)
    PHASE(1, 1, STAGE_B(0, kb + 128), VMCNT(6));  // g4
    PHASE(0, 2, STAGE_A(1, kb + 160), NOWAIT());  // g5: stage A(t+2,k1)
    PHASE(1, 2, STAGE_B(1, kb + 160), VMCNT(6));  // g6
    PHASE(0, 3, STAGE_A(2, kb + 192), NOWAIT());  // g7: stage A(t+3,k0)
    PHASE(1, 3, STAGE_B(2, kb + 192), VMCNT(6));  // g8
  }

  // ---- peeled last iteration (tiles 62,63): only tile63.k1 left to stage;
  // drain 6 -> 4 -> 0.
  PHASE(0, 0, STAGE_A(3, 4064), NOWAIT());
  PHASE(1, 0, STAGE_B(3, 4064), VMCNT(6));
  PHASE(0, 1, NOSTAGE(), NOWAIT());
  PHASE(1, 1, NOSTAGE(), VMCNT(4));
  PHASE(0, 2, NOSTAGE(), NOWAIT());
  PHASE(1, 2, NOSTAGE(), VMCNT(0));
  PHASE(0, 3, NOSTAGE(), NOWAIT());
  PHASE(1, 3, NOSTAGE(), NOWAIT());

  // ---- epilogue: D col = lane&15 (n), row = (lane>>4)*4 + reg (m) ----
  const int row0 = bm + wm * 128 + (lane >> 4) * 4;
  const int col0 = bn + wn * 64 + (lane & 15);
#pragma unroll
  for (int j = 0; j < 4; ++j) {
    const int col = col0 + j * 16;
    const float alpha = 0.02f * scale[col];
    const float beta = bias[col];
#pragma unroll
    for (int i8 = 0; i8 < 8; ++i8) {
      float* cp = C + (size_t)(row0 + i8 * 16) * N_TOT + col;
#pragma unroll
      for (int r = 0; r < 4; ++r)
        cp[(size_t)r * N_TOT] = acc[i8][j][r] * alpha + beta;
    }
  }
}

extern "C" void kernel_launch(void* const* d_in, const int* in_sizes, int n_in,
                              void* d_out, int out_size, void* d_ws,
                              size_t ws_size, hipStream_t stream) {
  const float* x = (const float*)d_in[0];     // [4,2048,4096] fp32
  const int* w = (const int*)d_in[1];         // [11008,4096] int32
  const float* scale = (const float*)d_in[2]; // [11008]
  const float* bias = (const float*)d_in[3];  // [1,11008]
  float* out = (float*)d_out;                 // [4,2048,11008] fp32

  half_t* xq = (half_t*)d_ws;                                    // 64 MB
  half_t* wq = (half_t*)((char*)d_ws + (size_t)M_TOT * K_TOT * sizeof(half_t));

  quantize_kernel<<<32768, 256, 0, stream>>>(x, xq);
  wconv_kernel<<<44032, 256, 0, stream>>>(w, wq);

  // 8192/256 = 32 ; 11008/256 = 43 ; 32*43 = 1376 blocks (8*172, XCD-exact)
  gemm_kernel<<<1376, 512, 0, stream>>>(xq, wq, scale, bias, out);
}

// Round 3
// 1142.983 us; speedup vs baseline: 1.2721x; 1.0478x over previous
//
#include <hip/hip_runtime.h>
#include <stdint.h>

typedef _Float16 half_t;
typedef _Float16 half8 __attribute__((ext_vector_type(8)));
typedef _Float16 half4v __attribute__((ext_vector_type(4)));
typedef float floatx4 __attribute__((ext_vector_type(4)));

#define M_TOT 8192
#define N_TOT 11008
#define K_TOT 4096

// ---------------- prolog 1: quantize activations fp32 -> f16 ----------------
__global__ __launch_bounds__(256) void quantize_kernel(
    const float* __restrict__ x, half_t* __restrict__ xq) {
  int i = blockIdx.x * blockDim.x + threadIdx.x;
  float4 v = ((const float4*)x)[i];
  float q0 = fminf(fmaxf(rintf(v.x / 0.02f), -32768.f), 32767.f);
  float q1 = fminf(fmaxf(rintf(v.y / 0.02f), -32768.f), 32767.f);
  float q2 = fminf(fmaxf(rintf(v.z / 0.02f), -32768.f), 32767.f);
  float q3 = fminf(fmaxf(rintf(v.w / 0.02f), -32768.f), 32767.f);
  half4v h;
  h.x = (half_t)q0; h.y = (half_t)q1; h.z = (half_t)q2; h.w = (half_t)q3;
  ((half4v*)xq)[i] = h;
}

// ---------------- prolog 2: weight int32 -> f16 ----------------
__global__ __launch_bounds__(256) void wconv_kernel(
    const int* __restrict__ w, half_t* __restrict__ wf) {
  int i = blockIdx.x * blockDim.x + threadIdx.x;
  int4 v = ((const int4*)w)[i];
  half4v h;
  h.x = (half_t)(float)v.x; h.y = (half_t)(float)v.y;
  h.z = (half_t)(float)v.z; h.w = (half_t)(float)v.w;
  ((half4v*)wf)[i] = h;
}

// ---------------- async 16B global->LDS ----------------
__device__ __forceinline__ void async16(const half_t* g, half_t* l) {
  __builtin_amdgcn_global_load_lds(
      (const __attribute__((address_space(1))) void*)g,
      (__attribute__((address_space(3))) void*)l, 16, 0, 0);
}

#define VMCNT(N) asm volatile("s_waitcnt vmcnt(" #N ")" ::: "memory")
#define BARX()                               \
  do {                                       \
    __builtin_amdgcn_s_barrier();            \
    __builtin_amdgcn_sched_barrier(0);       \
  } while (0)

// ---------------- main GEMM: 256x256 tile, QM-merged rolling pipeline -------
// C[M,N] = A[M,K] * W[N,K]^T with fused dequant epilogue.
//
// 512 threads = 8 waves (2M x 4N); wave tile 128x64, acc[8][4] f32x4.
// K in 32-wide slots; LDS ring of 4 slots per operand (A 4x[256][32]f16 in
// [0,32768), B same at +32768; 128 KiB total).
//
// BODY t (consume slot S=t&3, K=t*32), ONE barrier per body:
//   BARX
//   read af1 = A-frags (S, rows 64..127)        <- hides under QM0 MFMAs
//   stage A(slot S+3, K=(t+3)*32)               <- 2 global_load_lds
//   QM0: 16 MFMA (af0 x wf), i-major; after af0[i]'s last use, ROLL
//        af0[i] <- slot S+1 (WAR reg dep pins order; read hides under MFMAs)
//   stage B(slot S+3)
//   QM1: 16 MFMA (af1 x wf), j-major; after wf[j]'s last use, ROLL
//        wf[j] <- slot S+1
//   VMCNT(4)   (own 4 loads outstanding => all earlier bodies' stages done)
// Hazard map per body: read slots {S, S+1}, stage slot S+3 -- disjoint mod 4;
// single barrier + vmcnt(4)-before-barrier gives cross-wave visibility of
// slot S+1 before any wave's rolls in body t execute (staged at t-2,
// guaranteed by vmcnt at end of t-1). Rolled reads in flight across the
// barrier are safe: their slot (S+1) is not staged until body t+2, which is
// after their consuming lgkmcnt in body t+1.
//
// LDS swizzle [HW-verified 0-conflict]: 16B chunk kc of row r at phys slot
// kc ^ ((r>>1)&3); staging keeps LDS dest LINEAR and permutes the global
// source chunk instead.
__global__ __launch_bounds__(512) void gemm_kernel(
    const half_t* __restrict__ A,    // [M, K] quantized activations (f16)
    const half_t* __restrict__ W,    // [N, K] weights (f16)
    const float* __restrict__ scale, // [N]
    const float* __restrict__ bias,  // [N]
    float* __restrict__ C) {         // [M, N]
  __shared__ __align__(16) half_t lds[65536];  // 128 KiB

  const int tid = threadIdx.x;
  const int lane = tid & 63;
  const int wave = tid >> 6;
  const int wm = wave >> 2;  // 0..1
  const int wn = wave & 3;   // 0..3

  // XCD-chunked swizzle (1376 = 8*172) + 4-bm grouping for W-panel L2 reuse.
  int id = blockIdx.x;
  id = (id & 7) * 172 + (id >> 3);
  const int bm = ((id / 172) * 4 + ((id % 172) & 3)) * 256;
  const int bn = ((id % 172) >> 2) * 256;

  // ---- staging constants: thread owns linear chunks c0=tid, c1=tid+512 ----
  const int c0 = tid, c1 = tid + 512;
  const int r0 = c0 >> 2, r1 = c1 >> 2;
  const int kc0 = (c0 & 3) ^ ((r0 >> 1) & 3);
  const int kc1 = (c1 & 3) ^ ((r1 >> 1) & 3);
  const half_t* agA0 = A + (size_t)(bm + r0) * K_TOT + kc0 * 8;
  const half_t* agA1 = A + (size_t)(bm + r1) * K_TOT + kc1 * 8;
  const half_t* agB0 = W + (size_t)(bn + r0) * K_TOT + kc0 * 8;
  const half_t* agB1 = W + (size_t)(bn + r1) * K_TOT + kc1 * 8;

#define STAGE_A(S, KOFF)                                  \
  do {                                                    \
    async16(agA0 + (KOFF), lds + (S)*8192 + c0 * 8);      \
    async16(agA1 + (KOFF), lds + (S)*8192 + c1 * 8);      \
  } while (0)
#define STAGE_B(S, KOFF)                                          \
  do {                                                            \
    async16(agB0 + (KOFF), lds + 32768 + (S)*8192 + c0 * 8);      \
    async16(agB1 + (KOFF), lds + 32768 + (S)*8192 + c1 * 8);      \
  } while (0)
#define NOSTAGE() (void)0
#define NOWAIT() (void)0

  // ---- fragment-read constants (swizzle term reduces to fr bits) ----
  const int fr = lane & 15;
  const int kcs = (lane >> 4) ^ ((fr >> 1) & 3);
  const half_t* abase = lds + (wm * 128 + fr) * 32 + kcs * 8;
  const half_t* bbase = lds + 32768 + (wn * 64 + fr) * 32 + kcs * 8;

  half8 wf[4], af0[4], af1[4];
  floatx4 acc[8][4] = {};

#define BODY(S, SN, STGA, STGB, ROLL, WAIT)                               \
  do {                                                                    \
    BARX();                                                               \
    _Pragma("unroll") for (int i = 0; i < 4; ++i)                         \
        af1[i] = *(const half8*)(abase + (S)*8192 + 2048 + i * 512);      \
    STGA;                                                                 \
    __builtin_amdgcn_s_setprio(1);                                        \
    _Pragma("unroll") for (int i = 0; i < 4; ++i) {                       \
      _Pragma("unroll") for (int j = 0; j < 4; ++j)                       \
          acc[i][j] = __builtin_amdgcn_mfma_f32_16x16x32_f16(             \
              af0[i], wf[j], acc[i][j], 0, 0, 0);                         \
      if (ROLL)                                                           \
        af0[i] = *(const half8*)(abase + (SN)*8192 + i * 512);            \
    }                                                                     \
    __builtin_amdgcn_s_setprio(0);                                        \
    STGB;                                                                 \
    __builtin_amdgcn_s_setprio(1);                                        \
    _Pragma("unroll") for (int j = 0; j < 4; ++j) {                       \
      _Pragma("unroll") for (int i = 0; i < 4; ++i)                       \
          acc[4 + i][j] = __builtin_amdgcn_mfma_f32_16x16x32_f16(         \
              af1[i], wf[j], acc[4 + i][j], 0, 0, 0);                     \
      if (ROLL)                                                           \
        wf[j] = *(const half8*)(bbase + (SN)*8192 + j * 512);             \
    }                                                                     \
    __builtin_amdgcn_s_setprio(0);                                        \
    WAIT;                                                                 \
  } while (0)

  // ---- prologue: stage slots 0,1,2 (12 loads); vmcnt(4) -> slots 0,1
  // complete (slot1 needed by body0's rolls); preload slot-0 fragments.
  STAGE_A(0, 0);  STAGE_B(0, 0);
  STAGE_A(1, 32); STAGE_B(1, 32);
  STAGE_A(2, 64); STAGE_B(2, 64);
  VMCNT(4);
  BARX();
#pragma unroll
  for (int j = 0; j < 4; ++j) wf[j] = *(const half8*)(bbase + j * 512);
#pragma unroll
  for (int i = 0; i < 4; ++i) af0[i] = *(const half8*)(abase + i * 512);

  // ---- main loop: bodies t=0..123 (31 x 4), each stages slot for t+3 ----
  for (int it = 0; it < 31; ++it) {
    const int kb = it * 128;
    BODY(0, 1, STAGE_A(3, kb + 96),  STAGE_B(3, kb + 96),  true, VMCNT(4));
    BODY(1, 2, STAGE_A(0, kb + 128), STAGE_B(0, kb + 128), true, VMCNT(4));
    BODY(2, 3, STAGE_A(1, kb + 160), STAGE_B(1, kb + 160), true, VMCNT(4));
    BODY(3, 0, STAGE_A(2, kb + 192), STAGE_B(2, kb + 192), true, VMCNT(4));
  }
  // ---- drain: t=124 (last stage, K=4064), 125 (vmcnt 0), 126, 127 ----
  BODY(0, 1, STAGE_A(3, 4064), STAGE_B(3, 4064), true,  VMCNT(4));
  BODY(1, 2, NOSTAGE(),        NOSTAGE(),        true,  VMCNT(0));
  BODY(2, 3, NOSTAGE(),        NOSTAGE(),        true,  NOWAIT());
  BODY(3, 0, NOSTAGE(),        NOSTAGE(),        false, NOWAIT());

  // ---- epilogue: D col = lane&15 (n), row = (lane>>4)*4 + reg (m) ----
  const int row0 = bm + wm * 128 + (lane >> 4) * 4;
  const int col0 = bn + wn * 64 + (lane & 15);
#pragma unroll
  for (int j = 0; j < 4; ++j) {
    const int col = col0 + j * 16;
    const float alpha = 0.02f * scale[col];
    const float beta = bias[col];
#pragma unroll
    for (int i8 = 0; i8 < 8; ++i8) {
      float* cp = C + (size_t)(row0 + i8 * 16) * N_TOT + col;
#pragma unroll
      for (int r = 0; r < 4; ++r)
        cp[(size_t)r * N_TOT] = acc[i8][j][r] * alpha + beta;
    }
  }
}

extern "C" void kernel_launch(void* const* d_in, const int* in_sizes, int n_in,
                              void* d_out, int out_size, void* d_ws,
                              size_t ws_size, hipStream_t stream) {
  const float* x = (const float*)d_in[0];     // [4,2048,4096] fp32
  const int* w = (const int*)d_in[1];         // [11008,4096] int32
  const float* scale = (const float*)d_in[2]; // [11008]
  const float* bias = (const float*)d_in[3];  // [1,11008]
  float* out = (float*)d_out;                 // [4,2048,11008] fp32

  half_t* xq = (half_t*)d_ws;                                    // 64 MB
  half_t* wq = (half_t*)((char*)d_ws + (size_t)M_TOT * K_TOT * sizeof(half_t));

  quantize_kernel<<<32768, 256, 0, stream>>>(x, xq);
  wconv_kernel<<<44032, 256, 0, stream>>>(w, wq);

  // 8192/256 = 32 ; 11008/256 = 43 ; 32*43 = 1376 blocks (8*172, XCD-exact)
  gemm_kernel<<<1376, 512, 0, stream>>>(xq, wq, scale, bias, out);
}